// Round 14
// baseline (633.999 us; speedup 1.0000x reference)
//
#include <hip/hip_runtime.h>
#include <hip/hip_bf16.h>

#define N_NODES 50000
#define N_EDGES 800000
#define SCAN_NB ((N_NODES + 1023) / 1024)   // 49

// ---------- helpers ----------
__device__ __forceinline__ float rdlane(float v, int k) {
    return __uint_as_float(__builtin_amdgcn_readlane(__float_as_uint(v), k));
}
template <int CTRL>
__device__ __forceinline__ float dpp_addf(float v) {
    int x = __builtin_amdgcn_update_dpp(0, __float_as_int(v), CTRL, 0xF, 0xF, true);
    return v + __int_as_float(x);
}
#define DPP_QX1  0xB1   // quad_perm [1,0,3,2]
#define DPP_QX2  0x4E   // quad_perm [2,3,0,1]
#define DPP_HM   0x141  // row_half_mirror
#define DPP_RM   0x140  // row_mirror
#define DPP_ROR4 0x124  // row_ror:4
#define DPP_ROR8 0x128  // row_ror:8
__device__ __forceinline__ float dpp_sum16(float v) {
    v = dpp_addf<DPP_QX1>(v);
    v = dpp_addf<DPP_QX2>(v);
    v = dpp_addf<DPP_HM>(v);
    v = dpp_addf<DPP_RM>(v);
    return v;
}
__device__ __forceinline__ void bsum4(float& v0, float& v1, float& v2, float& v3) {
    #pragma unroll
    for (int m = 1; m < 64; m <<= 1) {
        v0 += __shfl_xor(v0, m);
        v1 += __shfl_xor(v1, m);
        v2 += __shfl_xor(v2, m);
        v3 += __shfl_xor(v3, m);
    }
}

// ---------- setup ----------
// fused: h = x@in_w+in_b ; xcur=x ; cnt=0 ; layer-0 t = h@rw1[:64]+rb1 (readlane GEMM)
__global__ void k_h01(const float* __restrict__ x, const float* __restrict__ in_w,
                      const float* __restrict__ in_b, const float* __restrict__ rw1,
                      const float* __restrict__ rb1, float* __restrict__ hb,
                      float4* __restrict__ xcur, unsigned* __restrict__ cntC,
                      float* __restrict__ t) {
    int tid = threadIdx.x;
    int wid = (blockIdx.x * blockDim.x + tid) >> 6;
    int lane = tid & 63;
    int n0 = wid * 4;
    if (n0 >= N_NODES) return;
    float iw0 = in_w[lane], iw1 = in_w[64 + lane], iw2 = in_w[128 + lane], iw3 = in_w[192 + lane];
    float ibl = in_b[lane];
    float hv[4];
    #pragma unroll
    for (int i = 0; i < 4; i++) {
        int n = n0 + i;
        hv[i] = 0.f;
        if (n < N_NODES) {
            float4 xv = ((const float4*)x)[n];
            hv[i] = ibl + xv.x * iw0 + xv.y * iw1 + xv.z * iw2 + xv.w * iw3;
            hb[n * 64 + lane] = hv[i];
            if (lane == 0) { xcur[n] = xv; cntC[n] = 0u; }
        }
    }
    float acc[4];
    #pragma unroll
    for (int i = 0; i < 4; i++) acc[i] = rb1[lane];
    for (int k = 0; k < 64; k++) {
        float w = rw1[k * 64 + lane];
        #pragma unroll
        for (int i = 0; i < 4; i++) acc[i] += rdlane(hv[i], k) * w;
    }
    #pragma unroll
    for (int i = 0; i < 4; i++) {
        int n = n0 + i;
        if (n < N_NODES) t[n * 64 + lane] = acc[i];
    }
}

// single-side count + per-edge rank (removes atomic from the write phase)
__global__ void k_count(const int* __restrict__ col, unsigned* __restrict__ cntC,
                        unsigned* __restrict__ rankC) {
    int e = blockIdx.x * blockDim.x + threadIdx.x;
    if (e < N_EDGES) rankC[e] = atomicAdd(&cntC[col[e]], 1u);
}

__global__ void __launch_bounds__(1024) k_scanA(const unsigned* __restrict__ cntC,
                                                unsigned* __restrict__ offsC,
                                                float* __restrict__ deg,
                                                unsigned* __restrict__ bs1) {
    __shared__ unsigned s1[1024];
    int tid = threadIdx.x;
    int i = blockIdx.x * 1024 + tid;
    unsigned v1 = (i < N_NODES) ? cntC[i] : 0u;
    s1[tid] = v1;
    __syncthreads();
    for (int off = 1; off < 1024; off <<= 1) {
        unsigned t1 = (tid >= off) ? s1[tid - off] : 0u;
        __syncthreads();
        s1[tid] += t1;
        __syncthreads();
    }
    if (i < N_NODES) {
        offsC[i] = s1[tid] - v1;
        deg[i]   = (float)(v1 + 1u);   // + self loop
    }
    if (tid == 1023) bs1[blockIdx.x] = s1[1023];
}

__global__ void k_scanB(const unsigned* __restrict__ bs1, unsigned* __restrict__ carry1,
                        unsigned* __restrict__ offsC) {
    int lane = threadIdx.x;  // 64 threads
    unsigned v1 = (lane < SCAN_NB) ? bs1[lane] : 0u;
    unsigned i1 = v1;
    #pragma unroll
    for (int off = 1; off < 64; off <<= 1) {
        unsigned t1 = __shfl_up(i1, off);
        if (lane >= off) i1 += t1;
    }
    if (lane < SCAN_NB) carry1[lane] = i1 - v1;
    if (lane == SCAN_NB - 1) offsC[N_NODES] = i1;
}

__global__ void __launch_bounds__(1024) k_scanC(unsigned* __restrict__ offsC,
                                                const unsigned* __restrict__ carry1) {
    int b = blockIdx.x;
    int i = b * 1024 + threadIdx.x;
    if (i < N_NODES) offsC[i] += carry1[b];
}

// pure write phase (no atomics): colRec4[slot] = {src, ea0, ea1, pad} packed 16B
__global__ void k_write(const int* __restrict__ row, const int* __restrict__ col,
                        const float* __restrict__ ea,
                        const unsigned* __restrict__ offsC, const unsigned* __restrict__ rankC,
                        float4* __restrict__ colRec4) {
    int e = blockIdx.x * blockDim.x + threadIdx.x;
    if (e >= N_EDGES) return;
    int r = row[e], c = col[e];
    float2 e2 = ((const float2*)ea)[e];
    colRec4[offsC[c] + rankC[e]] = make_float4(__int_as_float(r), e2.x, e2.y, 0.f);
}

// merged per-layer constants: blocks 0-3 score (M,u,v,w), blocks 4-7 value (Wp,bp)
__global__ void k_prep2(const float* __restrict__ qw, const float* __restrict__ qb,
                        const float* __restrict__ kw, const float* __restrict__ kb,
                        const float* __restrict__ vw, const float* __restrict__ vb,
                        const float* __restrict__ ow, float* __restrict__ cst,
                        float* __restrict__ cstV) {
    int m = threadIdx.x;
    int d = m & 15;
    if (blockIdx.x < 4) {
        int L = blockIdx.x;
        const float* qwl = qw + L * 256; const float* kwl = kw + L * 256;
        const float* qbl = qb + L * 64;  const float* kbl = kb + L * 64;
        float qa[4], ka[4];
        #pragma unroll
        for (int a = 0; a < 4; a++) { qa[a] = qwl[a * 64 + m]; ka[a] = kwl[a * 64 + m]; }
        float qbm = qbl[m], kbm = kbl[m];
        float vals[25];
        int idx = 0;
        #pragma unroll
        for (int a = 0; a < 4; a++)
            #pragma unroll
            for (int b = 0; b < 4; b++) vals[idx++] = qa[a] * ka[b];
        #pragma unroll
        for (int a = 0; a < 4; a++) vals[idx++] = qa[a] * kbm;
        #pragma unroll
        for (int b = 0; b < 4; b++) vals[idx++] = qbm * ka[b];
        vals[24] = qbm * kbm;
        #pragma unroll
        for (int i = 0; i < 25; i++) {
            float v = vals[i];
            v += __shfl_xor(v, 1); v += __shfl_xor(v, 2);
            v += __shfl_xor(v, 4); v += __shfl_xor(v, 8);
            vals[i] = v;
        }
        if (d == 0) {
            float* out = cst + L * 128 + (m >> 4) * 32;
            #pragma unroll
            for (int i = 0; i < 25; i++) out[i] = vals[i] * 0.25f;
        }
    } else {
        int L = blockIdx.x - 4;
        int h = m >> 4;
        const float* vwl = vw + L * 256;
        const float* vbl = vb + L * 64;
        float4 owv = ((const float4*)(ow + L * 256))[m];
        float vals[20];
        #pragma unroll
        for (int a = 0; a < 4; a++) {
            float v = vwl[a * 64 + m];
            vals[a * 4 + 0] = v * owv.x; vals[a * 4 + 1] = v * owv.y;
            vals[a * 4 + 2] = v * owv.z; vals[a * 4 + 3] = v * owv.w;
        }
        float b = vbl[m];
        vals[16] = b * owv.x; vals[17] = b * owv.y; vals[18] = b * owv.z; vals[19] = b * owv.w;
        #pragma unroll
        for (int i = 0; i < 20; i++) {
            float v = vals[i];
            v += __shfl_xor(v, 1); v += __shfl_xor(v, 2);
            v += __shfl_xor(v, 4); v += __shfl_xor(v, 8);
            vals[i] = v;
        }
        if (d == 0) {
            float* out = cstV + L * 128 + h * 32;
            #pragma unroll
            for (int i = 0; i < 20; i++) out[i] = vals[i];
        }
    }
}

// ---------- per-layer ----------
// layers 1..3: finalize prev layer, write h, compute this layer's t (readlane GEMM)
__global__ void k61(const float* __restrict__ att16, const float* __restrict__ sumexp,
                    const float4* __restrict__ x4b, const float* __restrict__ ob,
                    const float* __restrict__ g, const float* __restrict__ bb,
                    const float* __restrict__ resw, const float* __restrict__ in_w,
                    const float* __restrict__ in_b, float4* __restrict__ xcur,
                    const float* __restrict__ rw1, const float* __restrict__ rb1,
                    float* __restrict__ t, float* __restrict__ hb) {
    int tid = threadIdx.x;
    int wid = (blockIdx.x * blockDim.x + tid) >> 6;
    int lane = tid & 63;
    int n0 = wid * 4;
    if (n0 >= N_NODES) return;
    float iw0 = in_w[lane], iw1 = in_w[64 + lane], iw2 = in_w[128 + lane], iw3 = in_w[192 + lane];
    float ibl = in_b[lane];
    float z = sumexp[(lane & 15) >> 2];
    float ob0 = ob[0], ob1 = ob[1], ob2 = ob[2], ob3 = ob[3];
    float g0 = g[0], g1 = g[1], g2 = g[2], g3 = g[3];
    float bb0 = bb[0], bb1 = bb[1], bb2 = bb[2], bb3 = bb[3];
    float rw = resw[0];
    float hv[4];
    #pragma unroll
    for (int i = 0; i < 4; i++) {
        int n = n0 + i;
        float a = 0.f;
        if (n < N_NODES && lane < 16) a = att16[n * 16 + lane] / z;
        a = dpp_addf<DPP_ROR4>(a);
        a = dpp_addf<DPP_ROR8>(a);
        float y0 = rdlane(a, 0), y1 = rdlane(a, 1), y2 = rdlane(a, 2), y3 = rdlane(a, 3);
        hv[i] = 0.f;
        if (n < N_NODES) {
            float4 x4v = x4b[n];
            y0 += ob0 + x4v.x; y1 += ob1 + x4v.y;
            y2 += ob2 + x4v.z; y3 += ob3 + x4v.w;
            float mu = 0.25f * (y0 + y1 + y2 + y3);
            float d0 = y0 - mu, d1 = y1 - mu, d2 = y2 - mu, d3 = y3 - mu;
            float var = 0.25f * (d0 * d0 + d1 * d1 + d2 * d2 + d3 * d3);
            float rs = rsqrtf(var + 1e-5f);
            float4 xold = xcur[n];
            float nn0 = d0 * rs * g0 + bb0 + xold.x * rw;
            float nn1 = d1 * rs * g1 + bb1 + xold.y * rw;
            float nn2 = d2 * rs * g2 + bb2 + xold.z * rw;
            float nn3 = d3 * rs * g3 + bb3 + xold.w * rw;
            if (lane == 0) xcur[n] = make_float4(nn0, nn1, nn2, nn3);
            hv[i] = ibl + nn0 * iw0 + nn1 * iw1 + nn2 * iw2 + nn3 * iw3;
            hb[n * 64 + lane] = hv[i];
        }
    }
    float acc[4];
    #pragma unroll
    for (int i = 0; i < 4; i++) acc[i] = rb1[lane];
    for (int k = 0; k < 64; k++) {
        float w = rw1[k * 64 + lane];
        #pragma unroll
        for (int i = 0; i < 4; i++) acc[i] += rdlane(hv[i], k) * w;
    }
    #pragma unroll
    for (int i = 0; i < 4; i++) {
        int n = n0 + i;
        if (n < N_NODES) t[n * 64 + lane] = acc[i];
    }
}

// one edge per LANE in COL-SLOT order: colRec4 coalesced read, t row gather (LLC),
// msg4[slot] coalesced write. k23b then reads msg4 contiguously with no indirection.
__global__ void k2_cols(const float4* __restrict__ colRec4, const float* __restrict__ t,
                        const float* __restrict__ rw1, const float* __restrict__ rw2,
                        float4* __restrict__ msg4) {
    int p = blockIdx.x * blockDim.x + threadIdx.x;
    if (p >= N_EDGES) return;
    float4 rec = colRec4[p];
    int src = __float_as_int(rec.x);
    const float4* t4 = (const float4*)(t + (size_t)src * 64);
    float v0 = 0.f, v1 = 0.f, v2 = 0.f, v3 = 0.f;
    #pragma unroll
    for (int kc = 0; kc < 16; kc++) {
        float4 tv = t4[kc];
        #pragma unroll
        for (int j = 0; j < 4; j++) {
            int k = kc * 4 + j;
            float tk = (j == 0) ? tv.x : (j == 1) ? tv.y : (j == 2) ? tv.z : tv.w;
            float pre = tk + rec.y * rw1[64 * 64 + k] + rec.z * rw1[65 * 64 + k];
            float rr = fmaxf(pre, 0.f);
            v0 += rr * rw2[k * 64 + 0];
            v1 += rr * rw2[k * 64 + 1];
            v2 += rr * rw2[k * 64 + 2];
            v3 += rr * rw2[k * 64 + 3];
        }
    }
    msg4[p] = make_float4(v0, v1, v2, v3);
}

// fused self-loop + base + edge-gather + x4: quarter-wave per dst.
// msg4 range is CONTIGUOUS (col-slot order) — pure streaming read, no indirection.
__global__ void k23b(const unsigned* __restrict__ offsC, const float4* __restrict__ msg4,
                     const float* __restrict__ t, const float* __restrict__ hb,
                     const float* __restrict__ rw2, const float* __restrict__ sw,
                     const float* __restrict__ rb2, const float* __restrict__ sb,
                     const float* __restrict__ deg, float4* __restrict__ x4b,
                     float* __restrict__ sumexp) {
    __shared__ float s_rw2[64][4];
    __shared__ float s_sw[64][4];
    int tid = threadIdx.x;
    { int r = tid >> 2, c = tid & 3; s_rw2[r][c] = rw2[r * 64 + c]; s_sw[r][c] = sw[r * 256 + c]; }
    if (blockIdx.x == 0 && tid < 4) sumexp[tid] = 0.f;
    __syncthreads();
    int lane = tid & 63;
    int sub = lane >> 4, l16 = lane & 15;
    int gid = (blockIdx.x * blockDim.x + tid) >> 6;
    int c = gid * 4 + sub;
    if (c >= N_NODES) return;
    float4 tv = ((const float4*)(t + (size_t)c * 64))[l16];
    float4 hv = ((const float4*)(hb + (size_t)c * 64))[l16];
    float a0 = 0.f, a1 = 0.f, a2 = 0.f, a3 = 0.f;
    float b0 = 0.f, b1 = 0.f, b2 = 0.f, b3 = 0.f;
    #pragma unroll
    for (int j = 0; j < 4; j++) {
        int ch = l16 * 4 + j;
        float tk = (j == 0) ? tv.x : (j == 1) ? tv.y : (j == 2) ? tv.z : tv.w;
        float rr = fmaxf(tk, 0.f);
        a0 += rr * s_rw2[ch][0]; a1 += rr * s_rw2[ch][1];
        a2 += rr * s_rw2[ch][2]; a3 += rr * s_rw2[ch][3];
        float hk = (j == 0) ? hv.x : (j == 1) ? hv.y : (j == 2) ? hv.z : hv.w;
        b0 += hk * s_sw[ch][0]; b1 += hk * s_sw[ch][1];
        b2 += hk * s_sw[ch][2]; b3 += hk * s_sw[ch][3];
    }
    int beg = offsC[c], end = offsC[c + 1];
    for (int p = beg + l16; p < end; p += 16) {
        float4 m = msg4[p];
        a0 += m.x; a1 += m.y; a2 += m.z; a3 += m.w;
    }
    a0 = dpp_sum16(a0); a1 = dpp_sum16(a1); a2 = dpp_sum16(a2); a3 = dpp_sum16(a3);
    b0 = dpp_sum16(b0); b1 = dpp_sum16(b1); b2 = dpp_sum16(b2); b3 = dpp_sum16(b3);
    if (l16 == 0) {
        float idg = 1.f / deg[c];
        x4b[c] = make_float4(a0 * idg + b0 + rb2[0] + sb[0],
                             a1 * idg + b1 + rb2[1] + sb[1],
                             a2 * idg + b2 + rb2[2] + sb[2],
                             a3 * idg + b3 + rb2[3] + sb[3]);
    }
}

// attention gather, rank-4-factored V; WAVE per dst, 2-deep pipelined slot loop.
__global__ void k5_att(const unsigned* __restrict__ offsC, const float4* __restrict__ colRec4,
                       const float4* __restrict__ x4b, const float* __restrict__ cst,
                       const float* __restrict__ cstV, float* __restrict__ att16,
                       float* __restrict__ zbuf) {
    int tid = threadIdx.x;
    int lane = tid & 63;
    int sub = lane >> 4, d = lane & 15, h = d >> 2, a = d & 3;
    const float* C = cst + h * 32;
    int c = (blockIdx.x * blockDim.x + tid) >> 6;   // wave per dst
    if (c >= N_NODES) return;
    float4 xc = x4b[c];
    float g0 = xc.x * C[0]  + xc.y * C[1]  + xc.z * C[2]  + xc.w * C[3]  + C[16];
    float g1 = xc.x * C[4]  + xc.y * C[5]  + xc.z * C[6]  + xc.w * C[7]  + C[17];
    float g2 = xc.x * C[8]  + xc.y * C[9]  + xc.z * C[10] + xc.w * C[11] + C[18];
    float g3 = xc.x * C[12] + xc.y * C[13] + xc.z * C[14] + xc.w * C[15] + C[19];
    float base = C[20] * xc.x + C[21] * xc.y + C[22] * xc.z + C[23] * xc.w + C[24];
    int beg = offsC[c], end = offsC[c + 1];
    float S = 0.f, z = 0.f;
    int p = beg + sub;
    bool vld0 = p < end;
    float4 xr = make_float4(0.f, 0.f, 0.f, 0.f);
    if (vld0) xr = x4b[__float_as_int(colRec4[p].x)];
    int pn = p + 4;
    bool vld1 = pn < end;
    int rn = vld1 ? __float_as_int(colRec4[pn].x) : 0;
    while (vld0) {
        float4 xrn = make_float4(0.f, 0.f, 0.f, 0.f);
        if (vld1) xrn = x4b[rn];
        int pnn = pn + 4;
        bool vld2 = pnn < end;
        int rnn = vld2 ? __float_as_int(colRec4[pnn].x) : 0;
        float s = xr.x * g0 + xr.y * g1 + xr.z * g2 + xr.w * g3 + base;
        float ex = __expf(s);
        float xa = (a == 0) ? xr.x : (a == 1) ? xr.y : (a == 2) ? xr.z : xr.w;
        S += ex * xa;
        z += ex;
        xr = xrn; rn = rnn; vld0 = vld1; vld1 = vld2; pn = pnn;
    }
    S += __shfl_xor(S, 16); S += __shfl_xor(S, 32);
    z += __shfl_xor(z, 16); z += __shfl_xor(z, 32);
    const float* V = cstV + h * 32;
    float c0 = S * V[a * 4 + 0], c1 = S * V[a * 4 + 1];
    float c2 = S * V[a * 4 + 2], c3 = S * V[a * 4 + 3];
    c0 = dpp_addf<DPP_QX1>(c0); c1 = dpp_addf<DPP_QX1>(c1);
    c2 = dpp_addf<DPP_QX1>(c2); c3 = dpp_addf<DPP_QX1>(c3);
    c0 = dpp_addf<DPP_QX2>(c0); c1 = dpp_addf<DPP_QX2>(c1);
    c2 = dpp_addf<DPP_QX2>(c2); c3 = dpp_addf<DPP_QX2>(c3);
    float my = (a == 0) ? c0 : (a == 1) ? c1 : (a == 2) ? c2 : c3;
    if (sub == 0) {
        att16[c * 16 + d] = my + z * V[16 + a];
        if (a == 0) zbuf[c * 4 + h] = z;
    }
}

// reduce zbuf (N_NODES x 4) -> sumexp[4]; LDS block reduction, 49 atomics per head
__global__ void __launch_bounds__(1024) k_zred(const float4* __restrict__ zbuf,
                                               float* __restrict__ sumexp) {
    __shared__ float s[16][4];
    int tid = threadIdx.x;
    int i = blockIdx.x * 1024 + tid;
    float4 v = make_float4(0.f, 0.f, 0.f, 0.f);
    if (i < N_NODES) v = zbuf[i];
    bsum4(v.x, v.y, v.z, v.w);
    int w = tid >> 6;
    if ((tid & 63) == 0) { s[w][0] = v.x; s[w][1] = v.y; s[w][2] = v.z; s[w][3] = v.w; }
    __syncthreads();
    if (tid < 4) {
        float acc = 0.f;
        #pragma unroll
        for (int ww = 0; ww < 16; ww++) acc += s[ww][tid];
        atomicAdd(&sumexp[tid], acc);
    }
}

// final: finalize layer 3 then MLP head (readlane GEMM)
__global__ void k6pred(const float* __restrict__ att16, const float* __restrict__ sumexp,
                       const float4* __restrict__ x4b, const float* __restrict__ ob,
                       const float* __restrict__ g, const float* __restrict__ bb,
                       const float* __restrict__ resw, const float4* __restrict__ xcur,
                       const float* __restrict__ in_w, const float* __restrict__ in_b,
                       const float* __restrict__ w1, const float* __restrict__ b1,
                       const float* __restrict__ w2, const float* __restrict__ b2,
                       float* __restrict__ out) {
    int tid = threadIdx.x;
    int node = (blockIdx.x * blockDim.x + tid) >> 6;
    int lane = tid & 63;
    if (node >= N_NODES) return;
    float z = sumexp[(lane & 15) >> 2];
    float a = 0.f;
    if (lane < 16) a = att16[node * 16 + lane] / z;
    a = dpp_addf<DPP_ROR4>(a);
    a = dpp_addf<DPP_ROR8>(a);
    float y0 = rdlane(a, 0), y1 = rdlane(a, 1), y2 = rdlane(a, 2), y3 = rdlane(a, 3);
    float4 x4v = x4b[node];
    y0 += ob[0] + x4v.x; y1 += ob[1] + x4v.y;
    y2 += ob[2] + x4v.z; y3 += ob[3] + x4v.w;
    float mu = 0.25f * (y0 + y1 + y2 + y3);
    float d0 = y0 - mu, d1 = y1 - mu, d2 = y2 - mu, d3 = y3 - mu;
    float var = 0.25f * (d0 * d0 + d1 * d1 + d2 * d2 + d3 * d3);
    float rs = rsqrtf(var + 1e-5f);
    float4 xold = xcur[node];
    float rw = resw[0];
    float n0 = d0 * rs * g[0] + bb[0] + xold.x * rw;
    float n1 = d1 * rs * g[1] + bb[1] + xold.y * rw;
    float n2 = d2 * rs * g[2] + bb[2] + xold.z * rw;
    float n3 = d3 * rs * g[3] + bb[3] + xold.w * rw;
    float hv = in_b[lane] + n0 * in_w[lane] + n1 * in_w[64 + lane]
             + n2 * in_w[128 + lane] + n3 * in_w[192 + lane];
    int j2 = lane & 31;
    float m = b1[j2];
    for (int k = 0; k < 64; k++) m += rdlane(hv, k) * w1[k * 32 + j2];
    m = fmaxf(m, 0.f);
    float4 w2v = ((const float4*)w2)[j2];
    float v0 = m * w2v.x, v1 = m * w2v.y, v2 = m * w2v.z, v3 = m * w2v.w;
    bsum4(v0, v1, v2, v3);  // each j2 counted twice (both halves) -> *0.5
    float o0 = tanhf(0.5f * v0 + b2[0]) * 0.3f;
    float o1 = tanhf(0.5f * v1 + b2[1]) * 0.3f;
    float o2 = tanhf(0.5f * v2 + b2[2]) * 0.3f;
    float o3 = tanhf(0.5f * v3 + b2[3]) * 0.3f;
    if (lane == 0) ((float4*)out)[node] = make_float4(o0, o1, o2, o3);
}

// ---------- launch ----------
extern "C" void kernel_launch(void* const* d_in, const int* in_sizes, int n_in,
                              void* d_out, int out_size, void* d_ws, size_t ws_size,
                              hipStream_t stream) {
    const float* x        = (const float*)d_in[0];
    const int*   ei       = (const int*)d_in[1];
    const float* ea       = (const float*)d_in[2];
    const float* in_w     = (const float*)d_in[3];
    const float* in_b     = (const float*)d_in[4];
    const float* conv_rw1 = (const float*)d_in[5];
    const float* conv_rb1 = (const float*)d_in[6];
    const float* conv_rw2 = (const float*)d_in[7];
    const float* conv_rb2 = (const float*)d_in[8];
    // d_in[9..12] (imag path) dead: x4 = h4[:, :4] only touches real[:, :4]
    const float* conv_sw  = (const float*)d_in[13];
    const float* conv_sb  = (const float*)d_in[14];
    const float* att_qw   = (const float*)d_in[15];
    const float* att_qb   = (const float*)d_in[16];
    const float* att_kw   = (const float*)d_in[17];
    const float* att_kb   = (const float*)d_in[18];
    const float* att_vw   = (const float*)d_in[19];
    const float* att_vb   = (const float*)d_in[20];
    const float* att_ow   = (const float*)d_in[21];
    const float* att_ob   = (const float*)d_in[22];
    const float* ln_g     = (const float*)d_in[23];
    const float* ln_b     = (const float*)d_in[24];
    const float* out_w1   = (const float*)d_in[25];
    const float* out_b1   = (const float*)d_in[26];
    const float* out_w2   = (const float*)d_in[27];
    const float* out_b2   = (const float*)d_in[28];
    const float* res_w    = (const float*)d_in[29];

    const int* row = ei;
    const int* col = ei + N_EDGES;

    char* ws = (char*)d_ws;
    size_t off = 0;
    auto alloc = [&](size_t bytes) -> void* {
        void* p = ws + off;
        off = (off + bytes + 255) & ~(size_t)255;
        return p;
    };
    float*    deg      = (float*)alloc(N_NODES * 4);
    unsigned* cntC     = (unsigned*)alloc(N_NODES * 4);
    unsigned* offsC    = (unsigned*)alloc((N_NODES + 1) * 4);
    unsigned* bs1      = (unsigned*)alloc(SCAN_NB * 4);
    unsigned* carry1   = (unsigned*)alloc(SCAN_NB * 4);
    unsigned* rankC    = (unsigned*)alloc((size_t)N_EDGES * 4);
    float4*   colRec4  = (float4*)alloc((size_t)N_EDGES * 16);
    float4*   msg4     = (float4*)alloc((size_t)N_EDGES * 16);
    float*    tbuf     = (float*)alloc((size_t)N_NODES * 64 * 4);
    float*    hb       = (float*)alloc((size_t)N_NODES * 64 * 4);
    float*    att16    = (float*)alloc((size_t)N_NODES * 16 * 4);
    float*    zbuf     = (float*)alloc((size_t)N_NODES * 4 * 4);
    float4*   x4b      = (float4*)alloc((size_t)N_NODES * 16);
    float4*   xcur     = (float4*)alloc((size_t)N_NODES * 16);
    float*    cst      = (float*)alloc(4 * 128 * 4);
    float*    cstV     = (float*)alloc(4 * 128 * 4);
    float*    sumexp   = (float*)alloc(256);

    dim3 b256(256);
    int nodeBlocks  = (N_NODES + 3) / 4;        // wave per node
    int nodeBlocks4 = (N_NODES + 15) / 16;      // wave per 4 nodes
    int edgeTB      = (N_EDGES + 255) / 256;    // thread per edge
    int dstBlocks   = (N_NODES + 15) / 16;      // quarter-wave per dst
    int zredBlocks  = (N_NODES + 1023) / 1024;

    k_h01<<<nodeBlocks4, b256, 0, stream>>>(x, in_w, in_b, conv_rw1, conv_rb1,
                                            hb, xcur, cntC, tbuf);
    k_count<<<edgeTB, b256, 0, stream>>>(col, cntC, rankC);
    k_scanA<<<SCAN_NB, 1024, 0, stream>>>(cntC, offsC, deg, bs1);
    k_scanB<<<1, 64, 0, stream>>>(bs1, carry1, offsC);
    k_scanC<<<SCAN_NB, 1024, 0, stream>>>(offsC, carry1);
    k_write<<<edgeTB, b256, 0, stream>>>(row, col, ea, offsC, rankC, colRec4);
    k_prep2<<<8, 64, 0, stream>>>(att_qw, att_qb, att_kw, att_kb,
                                  att_vw, att_vb, att_ow, cst, cstV);

    for (int i = 0; i < 4; i++) {
        const float* rw1 = conv_rw1 + i * 66 * 64;
        const float* rb1 = conv_rb1 + i * 64;
        const float* rw2 = conv_rw2 + i * 64 * 64;
        const float* rb2 = conv_rb2 + i * 64;
        const float* swl = conv_sw + i * 64 * 256;
        const float* sbl = conv_sb + i * 256;

        if (i > 0) {
            k61<<<nodeBlocks4, b256, 0, stream>>>(att16, sumexp, x4b,
                                                  att_ob + (i - 1) * 4, ln_g + (i - 1) * 4,
                                                  ln_b + (i - 1) * 4, res_w + (i - 1),
                                                  in_w, in_b, xcur,
                                                  rw1, rb1, tbuf, hb);
        }
        k2_cols<<<edgeTB, b256, 0, stream>>>(colRec4, tbuf, rw1, rw2, msg4);
        k23b<<<dstBlocks, b256, 0, stream>>>(offsC, msg4, tbuf, hb,
                                             rw2, swl, rb2, sbl, deg, x4b, sumexp);
        k5_att<<<nodeBlocks, b256, 0, stream>>>(offsC, colRec4, x4b, cst + i * 128,
                                                cstV + i * 128, att16, zbuf);
        k_zred<<<zredBlocks, 1024, 0, stream>>>((const float4*)zbuf, sumexp);
    }
    k6pred<<<nodeBlocks, b256, 0, stream>>>(att16, sumexp, x4b, att_ob + 12, ln_g + 12,
                                            ln_b + 12, res_w + 3, xcur, in_w, in_b,
                                            out_w1, out_b1, out_w2, out_b2, (float*)d_out);
}

// Round 15
// 609.765 us; speedup vs baseline: 1.0397x; 1.0397x over previous
//
#include <hip/hip_runtime.h>
#include <hip/hip_bf16.h>

#define N_NODES 50000
#define N_EDGES 800000
#define SCAN_NB ((N_NODES + 1023) / 1024)   // 49

// ---------- helpers ----------
__device__ __forceinline__ float rdlane(float v, int k) {
    return __uint_as_float(__builtin_amdgcn_readlane(__float_as_uint(v), k));
}
template <int CTRL>
__device__ __forceinline__ float dpp_addf(float v) {
    int x = __builtin_amdgcn_update_dpp(0, __float_as_int(v), CTRL, 0xF, 0xF, true);
    return v + __int_as_float(x);
}
#define DPP_QX1  0xB1   // quad_perm [1,0,3,2]
#define DPP_QX2  0x4E   // quad_perm [2,3,0,1]
#define DPP_HM   0x141  // row_half_mirror
#define DPP_RM   0x140  // row_mirror
#define DPP_ROR4 0x124  // row_ror:4
#define DPP_ROR8 0x128  // row_ror:8
__device__ __forceinline__ float dpp_sum16(float v) {
    v = dpp_addf<DPP_QX1>(v);
    v = dpp_addf<DPP_QX2>(v);
    v = dpp_addf<DPP_HM>(v);
    v = dpp_addf<DPP_RM>(v);
    return v;
}
__device__ __forceinline__ void bsum4(float& v0, float& v1, float& v2, float& v3) {
    #pragma unroll
    for (int m = 1; m < 64; m <<= 1) {
        v0 += __shfl_xor(v0, m);
        v1 += __shfl_xor(v1, m);
        v2 += __shfl_xor(v2, m);
        v3 += __shfl_xor(v3, m);
    }
}

// ---------- setup ----------
// fused: h = x@in_w+in_b ; xcur=x ; cnts=0 ; layer-0 t = h@rw1[:64]+rb1 (readlane GEMM)
__global__ void k_h01(const float* __restrict__ x, const float* __restrict__ in_w,
                      const float* __restrict__ in_b, const float* __restrict__ rw1,
                      const float* __restrict__ rb1, float* __restrict__ hb,
                      float4* __restrict__ xcur, unsigned* __restrict__ cntC,
                      unsigned* __restrict__ cntR, float* __restrict__ t) {
    int tid = threadIdx.x;
    int wid = (blockIdx.x * blockDim.x + tid) >> 6;
    int lane = tid & 63;
    int n0 = wid * 4;
    if (n0 >= N_NODES) return;
    float iw0 = in_w[lane], iw1 = in_w[64 + lane], iw2 = in_w[128 + lane], iw3 = in_w[192 + lane];
    float ibl = in_b[lane];
    float hv[4];
    #pragma unroll
    for (int i = 0; i < 4; i++) {
        int n = n0 + i;
        hv[i] = 0.f;
        if (n < N_NODES) {
            float4 xv = ((const float4*)x)[n];
            hv[i] = ibl + xv.x * iw0 + xv.y * iw1 + xv.z * iw2 + xv.w * iw3;
            hb[n * 64 + lane] = hv[i];
            if (lane == 0) { xcur[n] = xv; cntC[n] = 0u; cntR[n] = 0u; }
        }
    }
    float acc[4];
    #pragma unroll
    for (int i = 0; i < 4; i++) acc[i] = rb1[lane];
    for (int k = 0; k < 64; k++) {
        float w = rw1[k * 64 + lane];
        #pragma unroll
        for (int i = 0; i < 4; i++) acc[i] += rdlane(hv[i], k) * w;
    }
    #pragma unroll
    for (int i = 0; i < 4; i++) {
        int n = n0 + i;
        if (n < N_NODES) t[n * 64 + lane] = acc[i];
    }
}

// count both sides + record per-edge ranks (removes atomics from the write phase)
__global__ void k_count(const int* __restrict__ row, const int* __restrict__ col,
                        unsigned* __restrict__ cntC, unsigned* __restrict__ cntR,
                        unsigned* __restrict__ rankC, unsigned* __restrict__ rankR) {
    int e = blockIdx.x * blockDim.x + threadIdx.x;
    if (e < N_EDGES) {
        rankC[e] = atomicAdd(&cntC[col[e]], 1u);
        rankR[e] = atomicAdd(&cntR[row[e]], 1u);
    }
}

__global__ void __launch_bounds__(1024) k_scanA(const unsigned* __restrict__ cntC,
                                                const unsigned* __restrict__ cntR,
                                                unsigned* __restrict__ offsC,
                                                unsigned* __restrict__ offsR,
                                                float* __restrict__ deg,
                                                unsigned* __restrict__ bs1,
                                                unsigned* __restrict__ bs2) {
    __shared__ unsigned s1[1024];
    __shared__ unsigned s2[1024];
    int tid = threadIdx.x;
    int i = blockIdx.x * 1024 + tid;
    unsigned v1 = (i < N_NODES) ? cntC[i] : 0u;
    unsigned v2 = (i < N_NODES) ? cntR[i] : 0u;
    s1[tid] = v1; s2[tid] = v2;
    __syncthreads();
    for (int off = 1; off < 1024; off <<= 1) {
        unsigned t1 = (tid >= off) ? s1[tid - off] : 0u;
        unsigned t2 = (tid >= off) ? s2[tid - off] : 0u;
        __syncthreads();
        s1[tid] += t1; s2[tid] += t2;
        __syncthreads();
    }
    if (i < N_NODES) {
        offsC[i] = s1[tid] - v1;
        offsR[i] = s2[tid] - v2;
        deg[i]   = (float)(v1 + 1u);   // + self loop
    }
    if (tid == 1023) { bs1[blockIdx.x] = s1[1023]; bs2[blockIdx.x] = s2[1023]; }
}

__global__ void k_scanB(const unsigned* __restrict__ bs1, const unsigned* __restrict__ bs2,
                        unsigned* __restrict__ carry1, unsigned* __restrict__ carry2,
                        unsigned* __restrict__ offsC, unsigned* __restrict__ offsR) {
    int lane = threadIdx.x;  // 64 threads
    unsigned v1 = (lane < SCAN_NB) ? bs1[lane] : 0u;
    unsigned v2 = (lane < SCAN_NB) ? bs2[lane] : 0u;
    unsigned i1 = v1, i2 = v2;
    #pragma unroll
    for (int off = 1; off < 64; off <<= 1) {
        unsigned t1 = __shfl_up(i1, off);
        unsigned t2 = __shfl_up(i2, off);
        if (lane >= off) { i1 += t1; i2 += t2; }
    }
    if (lane < SCAN_NB) { carry1[lane] = i1 - v1; carry2[lane] = i2 - v2; }
    if (lane == SCAN_NB - 1) { offsC[N_NODES] = i1; offsR[N_NODES] = i2; }
}

__global__ void __launch_bounds__(1024) k_scanC(unsigned* __restrict__ offsC,
                                                unsigned* __restrict__ offsR,
                                                const unsigned* __restrict__ carry1,
                                                const unsigned* __restrict__ carry2) {
    int b = blockIdx.x;
    int i = b * 1024 + threadIdx.x;
    if (i < N_NODES) { offsC[i] += carry1[b]; offsR[i] += carry2[b]; }
}

// pure write phase (no atomics): col-CSR records {src, rowSlot}; row-side packed
// eaSrc[rowSlot] = {ea0, ea1, src} for the row-sorted edge kernel.
__global__ void k_write(const int* __restrict__ row, const int* __restrict__ col,
                        const float* __restrict__ ea,
                        const unsigned* __restrict__ offsC, const unsigned* __restrict__ rankC,
                        const unsigned* __restrict__ offsR, const unsigned* __restrict__ rankR,
                        int2* __restrict__ colRec, float4* __restrict__ eaSrc) {
    int e = blockIdx.x * blockDim.x + threadIdx.x;
    if (e >= N_EDGES) return;
    int r = row[e], c = col[e];
    unsigned pR = offsR[r] + rankR[e];
    colRec[offsC[c] + rankC[e]] = make_int2(r, (int)pR);
    float2 e2 = ((const float2*)ea)[e];
    eaSrc[pR] = make_float4(e2.x, e2.y, __int_as_float(r), 0.f);
}

// merged per-layer constants: blocks 0-3 score (M,u,v,w), blocks 4-7 value (Wp,bp)
__global__ void k_prep2(const float* __restrict__ qw, const float* __restrict__ qb,
                        const float* __restrict__ kw, const float* __restrict__ kb,
                        const float* __restrict__ vw, const float* __restrict__ vb,
                        const float* __restrict__ ow, float* __restrict__ cst,
                        float* __restrict__ cstV) {
    int m = threadIdx.x;
    int d = m & 15;
    if (blockIdx.x < 4) {
        int L = blockIdx.x;
        const float* qwl = qw + L * 256; const float* kwl = kw + L * 256;
        const float* qbl = qb + L * 64;  const float* kbl = kb + L * 64;
        float qa[4], ka[4];
        #pragma unroll
        for (int a = 0; a < 4; a++) { qa[a] = qwl[a * 64 + m]; ka[a] = kwl[a * 64 + m]; }
        float qbm = qbl[m], kbm = kbl[m];
        float vals[25];
        int idx = 0;
        #pragma unroll
        for (int a = 0; a < 4; a++)
            #pragma unroll
            for (int b = 0; b < 4; b++) vals[idx++] = qa[a] * ka[b];
        #pragma unroll
        for (int a = 0; a < 4; a++) vals[idx++] = qa[a] * kbm;
        #pragma unroll
        for (int b = 0; b < 4; b++) vals[idx++] = qbm * ka[b];
        vals[24] = qbm * kbm;
        #pragma unroll
        for (int i = 0; i < 25; i++) {
            float v = vals[i];
            v += __shfl_xor(v, 1); v += __shfl_xor(v, 2);
            v += __shfl_xor(v, 4); v += __shfl_xor(v, 8);
            vals[i] = v;
        }
        if (d == 0) {
            float* out = cst + L * 128 + (m >> 4) * 32;
            #pragma unroll
            for (int i = 0; i < 25; i++) out[i] = vals[i] * 0.25f;
        }
    } else {
        int L = blockIdx.x - 4;
        int h = m >> 4;
        const float* vwl = vw + L * 256;
        const float* vbl = vb + L * 64;
        float4 owv = ((const float4*)(ow + L * 256))[m];
        float vals[20];
        #pragma unroll
        for (int a = 0; a < 4; a++) {
            float v = vwl[a * 64 + m];
            vals[a * 4 + 0] = v * owv.x; vals[a * 4 + 1] = v * owv.y;
            vals[a * 4 + 2] = v * owv.z; vals[a * 4 + 3] = v * owv.w;
        }
        float b = vbl[m];
        vals[16] = b * owv.x; vals[17] = b * owv.y; vals[18] = b * owv.z; vals[19] = b * owv.w;
        #pragma unroll
        for (int i = 0; i < 20; i++) {
            float v = vals[i];
            v += __shfl_xor(v, 1); v += __shfl_xor(v, 2);
            v += __shfl_xor(v, 4); v += __shfl_xor(v, 8);
            vals[i] = v;
        }
        if (d == 0) {
            float* out = cstV + L * 128 + h * 32;
            #pragma unroll
            for (int i = 0; i < 20; i++) out[i] = vals[i];
        }
    }
}

// ---------- per-layer ----------
// layers 1..3: finalize prev layer, write h, compute this layer's t (readlane GEMM)
__global__ void k61(const float* __restrict__ att16, const float* __restrict__ sumexp,
                    const float4* __restrict__ x4b, const float* __restrict__ ob,
                    const float* __restrict__ g, const float* __restrict__ bb,
                    const float* __restrict__ resw, const float* __restrict__ in_w,
                    const float* __restrict__ in_b, float4* __restrict__ xcur,
                    const float* __restrict__ rw1, const float* __restrict__ rb1,
                    float* __restrict__ t, float* __restrict__ hb) {
    int tid = threadIdx.x;
    int wid = (blockIdx.x * blockDim.x + tid) >> 6;
    int lane = tid & 63;
    int n0 = wid * 4;
    if (n0 >= N_NODES) return;
    float iw0 = in_w[lane], iw1 = in_w[64 + lane], iw2 = in_w[128 + lane], iw3 = in_w[192 + lane];
    float ibl = in_b[lane];
    float z = sumexp[(lane & 15) >> 2];
    float ob0 = ob[0], ob1 = ob[1], ob2 = ob[2], ob3 = ob[3];
    float g0 = g[0], g1 = g[1], g2 = g[2], g3 = g[3];
    float bb0 = bb[0], bb1 = bb[1], bb2 = bb[2], bb3 = bb[3];
    float rw = resw[0];
    float hv[4];
    #pragma unroll
    for (int i = 0; i < 4; i++) {
        int n = n0 + i;
        float a = 0.f;
        if (n < N_NODES && lane < 16) a = att16[n * 16 + lane] / z;
        a = dpp_addf<DPP_ROR4>(a);
        a = dpp_addf<DPP_ROR8>(a);
        float y0 = rdlane(a, 0), y1 = rdlane(a, 1), y2 = rdlane(a, 2), y3 = rdlane(a, 3);
        hv[i] = 0.f;
        if (n < N_NODES) {
            float4 x4v = x4b[n];
            y0 += ob0 + x4v.x; y1 += ob1 + x4v.y;
            y2 += ob2 + x4v.z; y3 += ob3 + x4v.w;
            float mu = 0.25f * (y0 + y1 + y2 + y3);
            float d0 = y0 - mu, d1 = y1 - mu, d2 = y2 - mu, d3 = y3 - mu;
            float var = 0.25f * (d0 * d0 + d1 * d1 + d2 * d2 + d3 * d3);
            float rs = rsqrtf(var + 1e-5f);
            float4 xold = xcur[n];
            float nn0 = d0 * rs * g0 + bb0 + xold.x * rw;
            float nn1 = d1 * rs * g1 + bb1 + xold.y * rw;
            float nn2 = d2 * rs * g2 + bb2 + xold.z * rw;
            float nn3 = d3 * rs * g3 + bb3 + xold.w * rw;
            if (lane == 0) xcur[n] = make_float4(nn0, nn1, nn2, nn3);
            hv[i] = ibl + nn0 * iw0 + nn1 * iw1 + nn2 * iw2 + nn3 * iw3;
            hb[n * 64 + lane] = hv[i];
        }
    }
    float acc[4];
    #pragma unroll
    for (int i = 0; i < 4; i++) acc[i] = rb1[lane];
    for (int k = 0; k < 64; k++) {
        float w = rw1[k * 64 + lane];
        #pragma unroll
        for (int i = 0; i < 4; i++) acc[i] += rdlane(hv[i], k) * w;
    }
    #pragma unroll
    for (int i = 0; i < 4; i++) {
        int n = n0 + i;
        if (n < N_NODES) t[n * 64 + lane] = acc[i];
    }
}

// one edge per LANE in ROW-SORTED order: ~4 distinct t rows per wave -> L1-resident
// broadcast loads; msg4[rowSlot] coalesced write. eaSrc packs {ea0, ea1, src}.
__global__ void k2_rows(const float4* __restrict__ eaSrc, const float* __restrict__ t,
                        const float* __restrict__ rw1, const float* __restrict__ rw2,
                        float4* __restrict__ msg4) {
    int p = blockIdx.x * blockDim.x + threadIdx.x;
    if (p >= N_EDGES) return;
    float4 es = eaSrc[p];
    int src = __float_as_int(es.z);
    const float4* t4 = (const float4*)(t + (size_t)src * 64);
    float v0 = 0.f, v1 = 0.f, v2 = 0.f, v3 = 0.f;
    #pragma unroll
    for (int kc = 0; kc < 16; kc++) {
        float4 tv = t4[kc];
        #pragma unroll
        for (int j = 0; j < 4; j++) {
            int k = kc * 4 + j;
            float tk = (j == 0) ? tv.x : (j == 1) ? tv.y : (j == 2) ? tv.z : tv.w;
            float pre = tk + es.x * rw1[64 * 64 + k] + es.y * rw1[65 * 64 + k];
            float rr = fmaxf(pre, 0.f);
            v0 += rr * rw2[k * 64 + 0];
            v1 += rr * rw2[k * 64 + 1];
            v2 += rr * rw2[k * 64 + 2];
            v3 += rr * rw2[k * 64 + 3];
        }
    }
    msg4[p] = make_float4(v0, v1, v2, v3);
}

// fused self-loop + base + edge-gather + x4: quarter-wave per dst
// (2-deep pipelined msg loop; reductions via DPP). colRec[p].y = row-slot.
__global__ void k23b(const unsigned* __restrict__ offsC, const int2* __restrict__ colRec,
                     const float4* __restrict__ msg4, const float* __restrict__ t,
                     const float* __restrict__ hb, const float* __restrict__ rw2,
                     const float* __restrict__ sw, const float* __restrict__ rb2,
                     const float* __restrict__ sb, const float* __restrict__ deg,
                     float4* __restrict__ x4b, float* __restrict__ sumexp) {
    __shared__ float s_rw2[64][4];
    __shared__ float s_sw[64][4];
    int tid = threadIdx.x;
    { int r = tid >> 2, c = tid & 3; s_rw2[r][c] = rw2[r * 64 + c]; s_sw[r][c] = sw[r * 256 + c]; }
    if (blockIdx.x == 0 && tid < 4) sumexp[tid] = 0.f;
    __syncthreads();
    int lane = tid & 63;
    int sub = lane >> 4, l16 = lane & 15;
    int gid = (blockIdx.x * blockDim.x + tid) >> 6;
    int c = gid * 4 + sub;
    if (c >= N_NODES) return;
    float4 tv = ((const float4*)(t + (size_t)c * 64))[l16];
    float4 hv = ((const float4*)(hb + (size_t)c * 64))[l16];
    float a0 = 0.f, a1 = 0.f, a2 = 0.f, a3 = 0.f;
    float b0 = 0.f, b1 = 0.f, b2 = 0.f, b3 = 0.f;
    #pragma unroll
    for (int j = 0; j < 4; j++) {
        int ch = l16 * 4 + j;
        float tk = (j == 0) ? tv.x : (j == 1) ? tv.y : (j == 2) ? tv.z : tv.w;
        float rr = fmaxf(tk, 0.f);
        a0 += rr * s_rw2[ch][0]; a1 += rr * s_rw2[ch][1];
        a2 += rr * s_rw2[ch][2]; a3 += rr * s_rw2[ch][3];
        float hk = (j == 0) ? hv.x : (j == 1) ? hv.y : (j == 2) ? hv.z : hv.w;
        b0 += hk * s_sw[ch][0]; b1 += hk * s_sw[ch][1];
        b2 += hk * s_sw[ch][2]; b3 += hk * s_sw[ch][3];
    }
    int beg = offsC[c], end = offsC[c + 1];
    int p = beg + l16;
    bool vld0 = p < end;
    float4 m = make_float4(0.f, 0.f, 0.f, 0.f);
    if (vld0) m = msg4[colRec[p].y];
    int pn = p + 16;
    bool vld1 = pn < end;
    int en = vld1 ? colRec[pn].y : 0;
    while (vld0) {
        float4 mn = make_float4(0.f, 0.f, 0.f, 0.f);
        if (vld1) mn = msg4[en];
        int pnn = pn + 16;
        bool vld2 = pnn < end;
        int enn = vld2 ? colRec[pnn].y : 0;
        a0 += m.x; a1 += m.y; a2 += m.z; a3 += m.w;
        m = mn; en = enn; vld0 = vld1; vld1 = vld2; pn = pnn;
    }
    a0 = dpp_sum16(a0); a1 = dpp_sum16(a1); a2 = dpp_sum16(a2); a3 = dpp_sum16(a3);
    b0 = dpp_sum16(b0); b1 = dpp_sum16(b1); b2 = dpp_sum16(b2); b3 = dpp_sum16(b3);
    if (l16 == 0) {
        float idg = 1.f / deg[c];
        x4b[c] = make_float4(a0 * idg + b0 + rb2[0] + sb[0],
                             a1 * idg + b1 + rb2[1] + sb[1],
                             a2 * idg + b2 + rb2[2] + sb[2],
                             a3 * idg + b3 + rb2[3] + sb[3]);
    }
}

// attention gather, rank-4-factored V; WAVE per dst, 2-deep pipelined slot loop.
__global__ void k5_att(const unsigned* __restrict__ offsC, const int2* __restrict__ colRec,
                       const float4* __restrict__ x4b, const float* __restrict__ cst,
                       const float* __restrict__ cstV, float* __restrict__ att16,
                       float* __restrict__ zbuf) {
    int tid = threadIdx.x;
    int lane = tid & 63;
    int sub = lane >> 4, d = lane & 15, h = d >> 2, a = d & 3;
    const float* C = cst + h * 32;
    int c = (blockIdx.x * blockDim.x + tid) >> 6;   // wave per dst
    if (c >= N_NODES) return;
    float4 xc = x4b[c];
    float g0 = xc.x * C[0]  + xc.y * C[1]  + xc.z * C[2]  + xc.w * C[3]  + C[16];
    float g1 = xc.x * C[4]  + xc.y * C[5]  + xc.z * C[6]  + xc.w * C[7]  + C[17];
    float g2 = xc.x * C[8]  + xc.y * C[9]  + xc.z * C[10] + xc.w * C[11] + C[18];
    float g3 = xc.x * C[12] + xc.y * C[13] + xc.z * C[14] + xc.w * C[15] + C[19];
    float base = C[20] * xc.x + C[21] * xc.y + C[22] * xc.z + C[23] * xc.w + C[24];
    int beg = offsC[c], end = offsC[c + 1];
    float S = 0.f, z = 0.f;
    int p = beg + sub;
    bool vld0 = p < end;
    float4 xr = make_float4(0.f, 0.f, 0.f, 0.f);
    if (vld0) xr = x4b[colRec[p].x];
    int pn = p + 4;
    bool vld1 = pn < end;
    int rn = vld1 ? colRec[pn].x : 0;
    while (vld0) {
        float4 xrn = make_float4(0.f, 0.f, 0.f, 0.f);
        if (vld1) xrn = x4b[rn];
        int pnn = pn + 4;
        bool vld2 = pnn < end;
        int rnn = vld2 ? colRec[pnn].x : 0;
        float s = xr.x * g0 + xr.y * g1 + xr.z * g2 + xr.w * g3 + base;
        float ex = __expf(s);
        float xa = (a == 0) ? xr.x : (a == 1) ? xr.y : (a == 2) ? xr.z : xr.w;
        S += ex * xa;
        z += ex;
        xr = xrn; rn = rnn; vld0 = vld1; vld1 = vld2; pn = pnn;
    }
    S += __shfl_xor(S, 16); S += __shfl_xor(S, 32);
    z += __shfl_xor(z, 16); z += __shfl_xor(z, 32);
    const float* V = cstV + h * 32;
    float c0 = S * V[a * 4 + 0], c1 = S * V[a * 4 + 1];
    float c2 = S * V[a * 4 + 2], c3 = S * V[a * 4 + 3];
    c0 = dpp_addf<DPP_QX1>(c0); c1 = dpp_addf<DPP_QX1>(c1);
    c2 = dpp_addf<DPP_QX1>(c2); c3 = dpp_addf<DPP_QX1>(c3);
    c0 = dpp_addf<DPP_QX2>(c0); c1 = dpp_addf<DPP_QX2>(c1);
    c2 = dpp_addf<DPP_QX2>(c2); c3 = dpp_addf<DPP_QX2>(c3);
    float my = (a == 0) ? c0 : (a == 1) ? c1 : (a == 2) ? c2 : c3;
    if (sub == 0) {
        att16[c * 16 + d] = my + z * V[16 + a];
        if (a == 0) zbuf[c * 4 + h] = z;
    }
}

// reduce zbuf (N_NODES x 4) -> sumexp[4]; LDS block reduction, 49 atomics per head
__global__ void __launch_bounds__(1024) k_zred(const float4* __restrict__ zbuf,
                                               float* __restrict__ sumexp) {
    __shared__ float s[16][4];
    int tid = threadIdx.x;
    int i = blockIdx.x * 1024 + tid;
    float4 v = make_float4(0.f, 0.f, 0.f, 0.f);
    if (i < N_NODES) v = zbuf[i];
    bsum4(v.x, v.y, v.z, v.w);
    int w = tid >> 6;
    if ((tid & 63) == 0) { s[w][0] = v.x; s[w][1] = v.y; s[w][2] = v.z; s[w][3] = v.w; }
    __syncthreads();
    if (tid < 4) {
        float acc = 0.f;
        #pragma unroll
        for (int ww = 0; ww < 16; ww++) acc += s[ww][tid];
        atomicAdd(&sumexp[tid], acc);
    }
}

// final: finalize layer 3 then MLP head (readlane GEMM)
__global__ void k6pred(const float* __restrict__ att16, const float* __restrict__ sumexp,
                       const float4* __restrict__ x4b, const float* __restrict__ ob,
                       const float* __restrict__ g, const float* __restrict__ bb,
                       const float* __restrict__ resw, const float4* __restrict__ xcur,
                       const float* __restrict__ in_w, const float* __restrict__ in_b,
                       const float* __restrict__ w1, const float* __restrict__ b1,
                       const float* __restrict__ w2, const float* __restrict__ b2,
                       float* __restrict__ out) {
    int tid = threadIdx.x;
    int node = (blockIdx.x * blockDim.x + tid) >> 6;
    int lane = tid & 63;
    if (node >= N_NODES) return;
    float z = sumexp[(lane & 15) >> 2];
    float a = 0.f;
    if (lane < 16) a = att16[node * 16 + lane] / z;
    a = dpp_addf<DPP_ROR4>(a);
    a = dpp_addf<DPP_ROR8>(a);
    float y0 = rdlane(a, 0), y1 = rdlane(a, 1), y2 = rdlane(a, 2), y3 = rdlane(a, 3);
    float4 x4v = x4b[node];
    y0 += ob[0] + x4v.x; y1 += ob[1] + x4v.y;
    y2 += ob[2] + x4v.z; y3 += ob[3] + x4v.w;
    float mu = 0.25f * (y0 + y1 + y2 + y3);
    float d0 = y0 - mu, d1 = y1 - mu, d2 = y2 - mu, d3 = y3 - mu;
    float var = 0.25f * (d0 * d0 + d1 * d1 + d2 * d2 + d3 * d3);
    float rs = rsqrtf(var + 1e-5f);
    float4 xold = xcur[node];
    float rw = resw[0];
    float n0 = d0 * rs * g[0] + bb[0] + xold.x * rw;
    float n1 = d1 * rs * g[1] + bb[1] + xold.y * rw;
    float n2 = d2 * rs * g[2] + bb[2] + xold.z * rw;
    float n3 = d3 * rs * g[3] + bb[3] + xold.w * rw;
    float hv = in_b[lane] + n0 * in_w[lane] + n1 * in_w[64 + lane]
             + n2 * in_w[128 + lane] + n3 * in_w[192 + lane];
    int j2 = lane & 31;
    float m = b1[j2];
    for (int k = 0; k < 64; k++) m += rdlane(hv, k) * w1[k * 32 + j2];
    m = fmaxf(m, 0.f);
    float4 w2v = ((const float4*)w2)[j2];
    float v0 = m * w2v.x, v1 = m * w2v.y, v2 = m * w2v.z, v3 = m * w2v.w;
    bsum4(v0, v1, v2, v3);  // each j2 counted twice (both halves) -> *0.5
    float o0 = tanhf(0.5f * v0 + b2[0]) * 0.3f;
    float o1 = tanhf(0.5f * v1 + b2[1]) * 0.3f;
    float o2 = tanhf(0.5f * v2 + b2[2]) * 0.3f;
    float o3 = tanhf(0.5f * v3 + b2[3]) * 0.3f;
    if (lane == 0) ((float4*)out)[node] = make_float4(o0, o1, o2, o3);
}

// ---------- launch ----------
extern "C" void kernel_launch(void* const* d_in, const int* in_sizes, int n_in,
                              void* d_out, int out_size, void* d_ws, size_t ws_size,
                              hipStream_t stream) {
    const float* x        = (const float*)d_in[0];
    const int*   ei       = (const int*)d_in[1];
    const float* ea       = (const float*)d_in[2];
    const float* in_w     = (const float*)d_in[3];
    const float* in_b     = (const float*)d_in[4];
    const float* conv_rw1 = (const float*)d_in[5];
    const float* conv_rb1 = (const float*)d_in[6];
    const float* conv_rw2 = (const float*)d_in[7];
    const float* conv_rb2 = (const float*)d_in[8];
    // d_in[9..12] (imag path) dead: x4 = h4[:, :4] only touches real[:, :4]
    const float* conv_sw  = (const float*)d_in[13];
    const float* conv_sb  = (const float*)d_in[14];
    const float* att_qw   = (const float*)d_in[15];
    const float* att_qb   = (const float*)d_in[16];
    const float* att_kw   = (const float*)d_in[17];
    const float* att_kb   = (const float*)d_in[18];
    const float* att_vw   = (const float*)d_in[19];
    const float* att_vb   = (const float*)d_in[20];
    const float* att_ow   = (const float*)d_in[21];
    const float* att_ob   = (const float*)d_in[22];
    const float* ln_g     = (const float*)d_in[23];
    const float* ln_b     = (const float*)d_in[24];
    const float* out_w1   = (const float*)d_in[25];
    const float* out_b1   = (const float*)d_in[26];
    const float* out_w2   = (const float*)d_in[27];
    const float* out_b2   = (const float*)d_in[28];
    const float* res_w    = (const float*)d_in[29];

    const int* row = ei;
    const int* col = ei + N_EDGES;

    char* ws = (char*)d_ws;
    size_t off = 0;
    auto alloc = [&](size_t bytes) -> void* {
        void* p = ws + off;
        off = (off + bytes + 255) & ~(size_t)255;
        return p;
    };
    float*    deg      = (float*)alloc(N_NODES * 4);
    unsigned* cntC     = (unsigned*)alloc(N_NODES * 4);
    unsigned* cntR     = (unsigned*)alloc(N_NODES * 4);
    unsigned* offsC    = (unsigned*)alloc((N_NODES + 1) * 4);
    unsigned* offsR    = (unsigned*)alloc((N_NODES + 1) * 4);
    unsigned* bs1      = (unsigned*)alloc(SCAN_NB * 4);
    unsigned* bs2      = (unsigned*)alloc(SCAN_NB * 4);
    unsigned* carry1   = (unsigned*)alloc(SCAN_NB * 4);
    unsigned* carry2   = (unsigned*)alloc(SCAN_NB * 4);
    unsigned* rankC    = (unsigned*)alloc((size_t)N_EDGES * 4);
    unsigned* rankR    = (unsigned*)alloc((size_t)N_EDGES * 4);
    int2*     colRec   = (int2*)alloc((size_t)N_EDGES * 8);
    float4*   eaSrc    = (float4*)alloc((size_t)N_EDGES * 16);
    float4*   msg4     = (float4*)alloc((size_t)N_EDGES * 16);
    float*    tbuf     = (float*)alloc((size_t)N_NODES * 64 * 4);
    float*    hb       = (float*)alloc((size_t)N_NODES * 64 * 4);
    float*    att16    = (float*)alloc((size_t)N_NODES * 16 * 4);
    float*    zbuf     = (float*)alloc((size_t)N_NODES * 4 * 4);
    float4*   x4b      = (float4*)alloc((size_t)N_NODES * 16);
    float4*   xcur     = (float4*)alloc((size_t)N_NODES * 16);
    float*    cst      = (float*)alloc(4 * 128 * 4);
    float*    cstV     = (float*)alloc(4 * 128 * 4);
    float*    sumexp   = (float*)alloc(256);

    dim3 b256(256);
    int nodeBlocks  = (N_NODES + 3) / 4;        // wave per node
    int nodeBlocks4 = (N_NODES + 15) / 16;      // wave per 4 nodes
    int edgeTB      = (N_EDGES + 255) / 256;    // thread per edge
    int dstBlocks   = (N_NODES + 15) / 16;      // quarter-wave per dst
    int zredBlocks  = (N_NODES + 1023) / 1024;

    k_h01<<<nodeBlocks4, b256, 0, stream>>>(x, in_w, in_b, conv_rw1, conv_rb1,
                                            hb, xcur, cntC, cntR, tbuf);
    k_count<<<edgeTB, b256, 0, stream>>>(row, col, cntC, cntR, rankC, rankR);
    k_scanA<<<SCAN_NB, 1024, 0, stream>>>(cntC, cntR, offsC, offsR, deg, bs1, bs2);
    k_scanB<<<1, 64, 0, stream>>>(bs1, bs2, carry1, carry2, offsC, offsR);
    k_scanC<<<SCAN_NB, 1024, 0, stream>>>(offsC, offsR, carry1, carry2);
    k_write<<<edgeTB, b256, 0, stream>>>(row, col, ea, offsC, rankC, offsR, rankR,
                                         colRec, eaSrc);
    k_prep2<<<8, 64, 0, stream>>>(att_qw, att_qb, att_kw, att_kb,
                                  att_vw, att_vb, att_ow, cst, cstV);

    for (int i = 0; i < 4; i++) {
        const float* rw1 = conv_rw1 + i * 66 * 64;
        const float* rb1 = conv_rb1 + i * 64;
        const float* rw2 = conv_rw2 + i * 64 * 64;
        const float* rb2 = conv_rb2 + i * 64;
        const float* swl = conv_sw + i * 64 * 256;
        const float* sbl = conv_sb + i * 256;

        if (i > 0) {
            k61<<<nodeBlocks4, b256, 0, stream>>>(att16, sumexp, x4b,
                                                  att_ob + (i - 1) * 4, ln_g + (i - 1) * 4,
                                                  ln_b + (i - 1) * 4, res_w + (i - 1),
                                                  in_w, in_b, xcur,
                                                  rw1, rb1, tbuf, hb);
        }
        k2_rows<<<edgeTB, b256, 0, stream>>>(eaSrc, tbuf, rw1, rw2, msg4);
        k23b<<<dstBlocks, b256, 0, stream>>>(offsC, colRec, msg4, tbuf, hb,
                                             rw2, swl, rb2, sbl, deg, x4b, sumexp);
        k5_att<<<nodeBlocks, b256, 0, stream>>>(offsC, colRec, x4b, cst + i * 128,
                                                cstV + i * 128, att16, zbuf);
        k_zred<<<zredBlocks, 1024, 0, stream>>>((const float4*)zbuf, sumexp);
    }
    k6pred<<<nodeBlocks, b256, 0, stream>>>(att16, sumexp, x4b, att_ob + 12, ln_g + 12,
                                            ln_b + 12, res_w + 3, xcur, in_w, in_b,
                                            out_w1, out_b1, out_w2, out_b2, (float*)d_out);
}